// Round 12
// baseline (55.460 us; speedup 1.0000x reference)
//
#include <hip/hip_runtime.h>
#include <hip/hip_bf16.h>

// Sliding-window block-causal attention — 4-way split window, LDS-free loop.
// B=2 H=8 S=4096 D=64, BLK=32, W=16. f32 I/O, bf16 MFMA, f32 softmax.
// WG = 256 thr = 4 waves, ALL on one q-block; wave w handles a 4-block
// quarter of the 16-block window. Loop body identical to verified v11
// (swapped QK^T, lane-local softmax, defer-max, P in regs, permuted V).
// 4-way flash-merge at the end. 2048 WGs -> 8 launched / ~5 resident WG/CU.

#define NH    8
#define SEQ   4096
#define DIM   64
#define NBLK  128
#define WIN   16

typedef __bf16 bf16x8 __attribute__((ext_vector_type(8)));
typedef float  f32x4  __attribute__((ext_vector_type(4)));

#define DTHR 8.0f   // defer-max threshold (exp2 domain)

__device__ __forceinline__ bf16x8 cvt8(f32x4 a, f32x4 b) {
    bf16x8 r;
#pragma unroll
    for (int j = 0; j < 4; ++j) { r[j] = (__bf16)a[j]; r[4 + j] = (__bf16)b[j]; }
    return r;
}

__global__ __launch_bounds__(256)
void sparse_attn_v12(const float* __restrict__ Q,
                     const float* __restrict__ K,
                     const float* __restrict__ V,
                     float* __restrict__ O)
{
    // XCD-chunked bijective swizzle (2048 WGs % 8 == 0)
    const int b  = (int)blockIdx.x;
    const int lg = (b & 7) * 256 + (b >> 3);
    const int bh = lg >> 7;              // 0..15
    const int nq = lg & 127;             // q-block

    const int t    = (int)threadIdx.x;
    const int w    = t >> 6;             // 0..3: window quarter
    const int lane = t & 63;
    const int l15  = lane & 15;
    const int l4   = lane >> 4;          // 0..3

    __shared__ float accsh[3][32][64];   // partials from waves 1..3 (24 KB)
    __shared__ float mlsh[3][4][64];     // m: [p][rt], l: [p][2+rt]   (3 KB)

    const size_t base = (size_t)bh * SEQ * DIM;
    const float SC = 0.125f * 1.44269504088896340736f;  // d^-0.5 * log2(e)

    // ---- Q fragments, pre-scaled (verified v11) ----
    bf16x8 qf[2][2];
#pragma unroll
    for (int rt = 0; rt < 2; ++rt) {
        const float* qp = Q + base + (size_t)(nq * 32 + rt * 16 + l15) * DIM + l4 * 8;
        f32x4 a0 = *(const f32x4*)qp        * SC;
        f32x4 b0 = *(const f32x4*)(qp + 4)  * SC;
        f32x4 a1 = *(const f32x4*)(qp + 32) * SC;
        f32x4 b1 = *(const f32x4*)(qp + 36) * SC;
        qf[rt][0] = cvt8(a0, b0);
        qf[rt][1] = cvt8(a1, b1);
    }

    f32x4 acc[2][4] = {};    // [rt][dt]: O[q=l15][d=dt*16+l4*4+r]
    float m[2]  = {-1e30f, -1e30f};
    float lp[2] = {0.f, 0.f};

    // ---- this wave's window quarter [lo, hi] (wave 3 owns the diagonal) ----
    const int kbs = (nq >= WIN - 1) ? nq - (WIN - 1) : 0;
    const int hiw = nq - (3 - w) * 4;
    const int lo  = (hiw - 3 > kbs) ? hiw - 3 : kbs;
    const int hi  = hiw;                 // if hi < kbs <= lo: zero iterations

    // V key permutation for this lane: slot j -> key kappa(l4, j) (verified v11)
    int vrow[8];
#pragma unroll
    for (int j = 0; j < 8; ++j)
        vrow[j] = (j < 4) ? (l4 * 4 + j) : (16 + l4 * 4 + (j - 4));

    for (int kb = lo; kb <= hi; ++kb) {
        // ---- K fragments (verified) ----
        bf16x8 kf[2][2];
#pragma unroll
        for (int kh = 0; kh < 2; ++kh) {
            const float* kp = K + base + (size_t)(kb * 32 + kh * 16 + l15) * DIM + l4 * 8;
            kf[kh][0] = cvt8(*(const f32x4*)kp,        *(const f32x4*)(kp + 4));
            kf[kh][1] = cvt8(*(const f32x4*)(kp + 32), *(const f32x4*)(kp + 36));
        }

        // ---- V fragments, permuted key map (verified) ----
        bf16x8 vf[4];
#pragma unroll
        for (int dt = 0; dt < 4; ++dt) {
            const float* vp = V + base + (size_t)(kb * 32) * DIM + dt * 16 + l15;
#pragma unroll
            for (int j = 0; j < 8; ++j)
                vf[dt][j] = (__bf16)vp[(size_t)vrow[j] * DIM];
        }

        // ---- swapped QK^T (verified): s = S^T, lane=(q=l15, key-group=l4) ----
        f32x4 s[2][2];
#pragma unroll
        for (int rt = 0; rt < 2; ++rt)
#pragma unroll
            for (int kh = 0; kh < 2; ++kh) {
                f32x4 a = {};
                a = __builtin_amdgcn_mfma_f32_16x16x32_bf16(kf[kh][0], qf[rt][0], a, 0, 0, 0);
                a = __builtin_amdgcn_mfma_f32_16x16x32_bf16(kf[kh][1], qf[rt][1], a, 0, 0, 0);
                s[rt][kh] = a;
            }

        // ---- causal mask (diagonal block only; only wave 3 reaches it) ----
        if (kb == nq) {
#pragma unroll
            for (int rt = 0; rt < 2; ++rt)
#pragma unroll
                for (int kh = 0; kh < 2; ++kh)
#pragma unroll
                    for (int r = 0; r < 4; ++r)
                        if (kh * 16 + l4 * 4 + r > rt * 16 + l15)
                            s[rt][kh][r] = -1e30f;
        }

        // ---- defer-max check (lane-local, verified) ----
        bool ok = true;
#pragma unroll
        for (int rt = 0; rt < 2; ++rt)
#pragma unroll
            for (int kh = 0; kh < 2; ++kh)
#pragma unroll
                for (int r = 0; r < 4; ++r)
                    ok &= (s[rt][kh][r] <= m[rt] + DTHR);

        if (!__all(ok)) {
#pragma unroll
            for (int rt = 0; rt < 2; ++rt) {
                float t0 = -1e30f;
#pragma unroll
                for (int kh = 0; kh < 2; ++kh)
#pragma unroll
                    for (int r = 0; r < 4; ++r) t0 = fmaxf(t0, s[rt][kh][r]);
                t0 = fmaxf(t0, __shfl_xor(t0, 16));
                t0 = fmaxf(t0, __shfl_xor(t0, 32));
                const float mn = fmaxf(m[rt], t0);
                const float al = exp2f(m[rt] - mn);
                m[rt] = mn;
                lp[rt] *= al;
#pragma unroll
                for (int dt = 0; dt < 4; ++dt)
#pragma unroll
                    for (int r = 0; r < 4; ++r) acc[rt][dt][r] *= al;
            }
        }

        // ---- exp2 + pack P (slot j: kh=j>>2, r=j&3) (verified) ----
        bf16x8 pbf[2];
#pragma unroll
        for (int rt = 0; rt < 2; ++rt) {
            float psum = 0.f;
#pragma unroll
            for (int j = 0; j < 8; ++j) {
                const float p = exp2f(s[rt][j >> 2][j & 3] - m[rt]);
                psum += p;
                pbf[rt][j] = (__bf16)p;
            }
            lp[rt] += psum;
        }

        // ---- PV (verified): mfma(A=V_perm, B=P_regs) ----
#pragma unroll
        for (int rt = 0; rt < 2; ++rt)
#pragma unroll
            for (int dt = 0; dt < 4; ++dt)
                acc[rt][dt] = __builtin_amdgcn_mfma_f32_16x16x32_bf16(
                    vf[dt], pbf[rt], acc[rt][dt], 0, 0, 0);
    }

    // ---- final l reduction (verified) ----
    float l[2];
#pragma unroll
    for (int rt = 0; rt < 2; ++rt) {
        float ps = lp[rt];
        ps += __shfl_xor(ps, 16);
        ps += __shfl_xor(ps, 32);
        l[rt] = ps;
    }

    // ---- 4-way flash-merge (generalizes verified 2-way) ----
    if (w > 0) {
        const int p = w - 1;
#pragma unroll
        for (int rt = 0; rt < 2; ++rt) {
            mlsh[p][rt][lane]     = m[rt];
            mlsh[p][2 + rt][lane] = l[rt];
#pragma unroll
            for (int dt = 0; dt < 4; ++dt)
#pragma unroll
                for (int r = 0; r < 4; ++r)
                    accsh[p][rt * 16 + dt * 4 + r][lane] = acc[rt][dt][r];
        }
    }

    __syncthreads();

    if (w == 0) {
#pragma unroll
        for (int rt = 0; rt < 2; ++rt) {
            float mn = m[rt];
#pragma unroll
            for (int p = 0; p < 3; ++p) mn = fmaxf(mn, mlsh[p][rt][lane]);
            const float a0 = exp2f(m[rt] - mn);
            float lsum = l[rt] * a0;
            float ap[3];
#pragma unroll
            for (int p = 0; p < 3; ++p) {
                ap[p] = exp2f(mlsh[p][rt][lane] - mn);
                lsum += mlsh[p][2 + rt][lane] * ap[p];
            }
            const float inv = 1.0f / lsum;
            float* op = O + base + (size_t)(nq * 32 + rt * 16 + l15) * DIM + l4 * 4;
#pragma unroll
            for (int dt = 0; dt < 4; ++dt) {
                f32x4 v;
#pragma unroll
                for (int r = 0; r < 4; ++r) {
                    float x = acc[rt][dt][r] * a0;
#pragma unroll
                    for (int p = 0; p < 3; ++p)
                        x += accsh[p][rt * 16 + dt * 4 + r][lane] * ap[p];
                    v[r] = x * inv;
                }
                *(f32x4*)(op + dt * 16) = v;
            }
        }
    }
}

extern "C" void kernel_launch(void* const* d_in, const int* in_sizes, int n_in,
                              void* d_out, int out_size, void* d_ws, size_t ws_size,
                              hipStream_t stream)
{
    const float* Q = (const float*)d_in[0];
    const float* K = (const float*)d_in[1];
    const float* V = (const float*)d_in[2];
    float*       O = (float*)d_out;

    const int nwg = 2 * NH * NBLK;   // 2048 WGs x 256 thr
    hipLaunchKernelGGL(sparse_attn_v12, dim3(nwg), dim3(256), 0, stream,
                       Q, K, V, O);
}

// Round 14
// 50.684 us; speedup vs baseline: 1.0942x; 1.0942x over previous
//
#include <hip/hip_runtime.h>
#include <hip/hip_bf16.h>

// Sliding-window block-causal attention — swapped-operand MFMA, LDS-free loop,
// UNROLLED full-window fast path (compiler software-pipelines the 8 iters).
// B=2 H=8 S=4096 D=64, BLK=32, W=16. f32 I/O, bf16 MFMA, f32 softmax.
// WG = 256 thr (4 waves) = 2 q-blocks x 2 half-windows; 1024 WGs. (v11 base)

#define NH    8
#define SEQ   4096
#define DIM   64
#define NBLK  128
#define WIN   16
#define QG    2
#define GROUPS (NBLK / QG)   // 64

typedef __bf16 bf16x8 __attribute__((ext_vector_type(8)));
typedef float  f32x4  __attribute__((ext_vector_type(4)));

#define DTHR 8.0f   // defer-max threshold (exp2 domain)

__device__ __forceinline__ bf16x8 cvt8(f32x4 a, f32x4 b) {
    bf16x8 r;
#pragma unroll
    for (int j = 0; j < 4; ++j) { r[j] = (__bf16)a[j]; r[4 + j] = (__bf16)b[j]; }
    return r;
}

__global__ __launch_bounds__(256)
void sparse_attn_v13(const float* __restrict__ Q,
                     const float* __restrict__ K,
                     const float* __restrict__ V,
                     float* __restrict__ O)
{
    // XCD-chunked bijective swizzle (1024 WGs % 8 == 0)
    const int b  = (int)blockIdx.x;
    const int lg = (b & 7) * 128 + (b >> 3);
    const int bh = lg >> 6;              // 0..15
    const int n0 = (lg & 63) * QG;       // group's first q-block

    const int t    = (int)threadIdx.x;
    const int wave = t >> 6;             // 0..3
    const int lane = t & 63;
    const int l15  = lane & 15;
    const int l4   = lane >> 4;          // 0..3
    const int qi   = wave >> 1;          // q-block within group: 0..1
    const int half = wave & 1;           // window half
    const int nq   = n0 + qi;

    __shared__ float accsh[QG][32][64];  // (16 KB)
    __shared__ float mlsh[QG][4][64];    // (2 KB)

    const size_t base = (size_t)bh * SEQ * DIM;
    const float SC = 0.125f * 1.44269504088896340736f;  // d^-0.5 * log2(e)

    // ---- Q fragments, pre-scaled (verified v11) ----
    bf16x8 qf[2][2];
#pragma unroll
    for (int rt = 0; rt < 2; ++rt) {
        const float* qp = Q + base + (size_t)(nq * 32 + rt * 16 + l15) * DIM + l4 * 8;
        f32x4 a0 = *(const f32x4*)qp        * SC;
        f32x4 b0 = *(const f32x4*)(qp + 4)  * SC;
        f32x4 a1 = *(const f32x4*)(qp + 32) * SC;
        f32x4 b1 = *(const f32x4*)(qp + 36) * SC;
        qf[rt][0] = cvt8(a0, b0);
        qf[rt][1] = cvt8(a1, b1);
    }

    f32x4 acc[2][4] = {};    // [rt][dt]: O[q=l15][d=dt*16+l4*4+r]
    float m[2]  = {-1e30f, -1e30f};
    float lp[2] = {0.f, 0.f};

    const int kbs = (nq >= WIN - 1) ? nq - (WIN - 1) : 0;
    const int lo  = half ? ((nq - 7 > kbs) ? nq - 7 : kbs) : kbs;
    const int hi  = half ? nq : nq - 8;

    // V key permutation (verified v11): slot j -> key kappa(l4, j)
    int vrow[8];
#pragma unroll
    for (int j = 0; j < 8; ++j)
        vrow[j] = (j < 4) ? (l4 * 4 + j) : (16 + l4 * 4 + (j - 4));

#define BODY(KB)                                                                  \
    {                                                                             \
        const int kb_ = (KB);                                                     \
        bf16x8 kf[2][2];                                                          \
        _Pragma("unroll")                                                         \
        for (int kh = 0; kh < 2; ++kh) {                                          \
            const float* kp = K + base +                                          \
                (size_t)(kb_ * 32 + kh * 16 + l15) * DIM + l4 * 8;                \
            kf[kh][0] = cvt8(*(const f32x4*)kp,        *(const f32x4*)(kp + 4));  \
            kf[kh][1] = cvt8(*(const f32x4*)(kp + 32), *(const f32x4*)(kp + 36)); \
        }                                                                         \
        bf16x8 vf[4];                                                             \
        _Pragma("unroll")                                                         \
        for (int dt = 0; dt < 4; ++dt) {                                          \
            const float* vp = V + base + (size_t)(kb_ * 32) * DIM + dt * 16 + l15;\
            _Pragma("unroll")                                                     \
            for (int j = 0; j < 8; ++j)                                           \
                vf[dt][j] = (__bf16)vp[(size_t)vrow[j] * DIM];                    \
        }                                                                         \
        f32x4 s[2][2];                                                            \
        _Pragma("unroll")                                                         \
        for (int rt = 0; rt < 2; ++rt)                                            \
            _Pragma("unroll")                                                     \
            for (int kh = 0; kh < 2; ++kh) {                                      \
                f32x4 a = {};                                                     \
                a = __builtin_amdgcn_mfma_f32_16x16x32_bf16(                      \
                        kf[kh][0], qf[rt][0], a, 0, 0, 0);                        \
                a = __builtin_amdgcn_mfma_f32_16x16x32_bf16(                      \
                        kf[kh][1], qf[rt][1], a, 0, 0, 0);                        \
                s[rt][kh] = a;                                                    \
            }                                                                     \
        if (kb_ == nq) {                                                          \
            _Pragma("unroll")                                                     \
            for (int rt = 0; rt < 2; ++rt)                                        \
                _Pragma("unroll")                                                 \
                for (int kh = 0; kh < 2; ++kh)                                    \
                    _Pragma("unroll")                                             \
                    for (int r = 0; r < 4; ++r)                                   \
                        if (kh * 16 + l4 * 4 + r > rt * 16 + l15)                 \
                            s[rt][kh][r] = -1e30f;                                \
        }                                                                         \
        bool ok = true;                                                           \
        _Pragma("unroll")                                                         \
        for (int rt = 0; rt < 2; ++rt)                                            \
            _Pragma("unroll")                                                     \
            for (int kh = 0; kh < 2; ++kh)                                        \
                _Pragma("unroll")                                                 \
                for (int r = 0; r < 4; ++r)                                       \
                    ok &= (s[rt][kh][r] <= m[rt] + DTHR);                         \
        if (!__all(ok)) {                                                         \
            _Pragma("unroll")                                                     \
            for (int rt = 0; rt < 2; ++rt) {                                      \
                float t0 = -1e30f;                                                \
                _Pragma("unroll")                                                 \
                for (int kh = 0; kh < 2; ++kh)                                    \
                    _Pragma("unroll")                                             \
                    for (int r = 0; r < 4; ++r) t0 = fmaxf(t0, s[rt][kh][r]);     \
                t0 = fmaxf(t0, __shfl_xor(t0, 16));                               \
                t0 = fmaxf(t0, __shfl_xor(t0, 32));                               \
                const float mn = fmaxf(m[rt], t0);                                \
                const float al = exp2f(m[rt] - mn);                               \
                m[rt] = mn;                                                       \
                lp[rt] *= al;                                                     \
                _Pragma("unroll")                                                 \
                for (int dt = 0; dt < 4; ++dt)                                    \
                    _Pragma("unroll")                                             \
                    for (int r = 0; r < 4; ++r) acc[rt][dt][r] *= al;             \
            }                                                                     \
        }                                                                         \
        bf16x8 pbf[2];                                                            \
        _Pragma("unroll")                                                         \
        for (int rt = 0; rt < 2; ++rt) {                                          \
            float psum = 0.f;                                                     \
            _Pragma("unroll")                                                     \
            for (int j = 0; j < 8; ++j) {                                         \
                const float p = exp2f(s[rt][j >> 2][j & 3] - m[rt]);              \
                psum += p;                                                        \
                pbf[rt][j] = (__bf16)p;                                           \
            }                                                                     \
            lp[rt] += psum;                                                       \
        }                                                                         \
        _Pragma("unroll")                                                         \
        for (int rt = 0; rt < 2; ++rt)                                            \
            _Pragma("unroll")                                                     \
            for (int dt = 0; dt < 4; ++dt)                                        \
                acc[rt][dt] = __builtin_amdgcn_mfma_f32_16x16x32_bf16(            \
                    vf[dt], pbf[rt], acc[rt][dt], 0, 0, 0);                       \
    }

    if (hi - lo == 7) {
        // fast path (120/128 q-blocks): straight-line 8 iters, compiler pipelines
#pragma unroll
        for (int i = 0; i < 8; ++i) BODY(lo + i);
    } else {
        for (int kbr = lo; kbr <= hi; ++kbr) BODY(kbr);
    }
#undef BODY

    // ---- final l reduction (verified) ----
    float l[2];
#pragma unroll
    for (int rt = 0; rt < 2; ++rt) {
        float ps = lp[rt];
        ps += __shfl_xor(ps, 16);
        ps += __shfl_xor(ps, 32);
        l[rt] = ps;
    }

    // ---- flash-merge of the two halves (verified v11) ----
    if (half == 1) {
#pragma unroll
        for (int rt = 0; rt < 2; ++rt) {
            mlsh[qi][rt][lane]     = m[rt];
            mlsh[qi][2 + rt][lane] = l[rt];
#pragma unroll
            for (int dt = 0; dt < 4; ++dt)
#pragma unroll
                for (int r = 0; r < 4; ++r)
                    accsh[qi][rt * 16 + dt * 4 + r][lane] = acc[rt][dt][r];
        }
    }

    __syncthreads();

    if (half == 0) {
#pragma unroll
        for (int rt = 0; rt < 2; ++rt) {
            const float m2 = mlsh[qi][rt][lane];
            const float l2 = mlsh[qi][2 + rt][lane];
            const float mn = fmaxf(m[rt], m2);
            const float a1 = exp2f(m[rt] - mn);
            const float a2 = exp2f(m2 - mn);
            const float inv = 1.0f / (l[rt] * a1 + l2 * a2);
            float* op = O + base + (size_t)(nq * 32 + rt * 16 + l15) * DIM + l4 * 4;
#pragma unroll
            for (int dt = 0; dt < 4; ++dt) {
                f32x4 v;
#pragma unroll
                for (int r = 0; r < 4; ++r)
                    v[r] = (acc[rt][dt][r] * a1 +
                            accsh[qi][rt * 16 + dt * 4 + r][lane] * a2) * inv;
                *(f32x4*)(op + dt * 16) = v;
            }
        }
    }
}

extern "C" void kernel_launch(void* const* d_in, const int* in_sizes, int n_in,
                              void* d_out, int out_size, void* d_ws, size_t ws_size,
                              hipStream_t stream)
{
    const float* Q = (const float*)d_in[0];
    const float* K = (const float*)d_in[1];
    const float* V = (const float*)d_in[2];
    float*       O = (float*)d_out;

    const int nwg = 2 * NH * GROUPS;   // 1024 WGs x 256 thr
    hipLaunchKernelGGL(sparse_attn_v13, dim3(nwg), dim3(256), 0, stream,
                       Q, K, V, O);
}

// Round 15
// 36.990 us; speedup vs baseline: 1.4993x; 1.3702x over previous
//
#include <hip/hip_runtime.h>
#include <hip/hip_bf16.h>

// Sliding-window block-causal attention — WG-shared LDS staging, 1 barrier/iter,
// issue-early/write-late double-buffer, in-register swapped softmax (v11 core).
// B=2 H=8 S=4096 D=64, BLK=32, W=16. f32 I/O, bf16 MFMA, f32 softmax.
// WG = 256 thr = 4 waves, wave w owns q-block n0+w; union window (19 blocks)
// staged cooperatively once per WG (vs 4x per-wave in v13). 512 WGs.

#define NH    8
#define SEQ   4096
#define DIM   64
#define NBLK  128
#define WIN   16
#define QG    4
#define GROUPS (NBLK / QG)   // 32

typedef __bf16 bf16x8 __attribute__((ext_vector_type(8)));
typedef __bf16 bf16x4 __attribute__((ext_vector_type(4)));
typedef float  f32x4  __attribute__((ext_vector_type(4)));
typedef unsigned short u16;
typedef unsigned int   u32;

#define KSTR 72   // Kt row stride (u16): 144B rows, 16B-aligned (b128-safe)
#define VSTR 40   // Vt row stride (u16): 80B rows, 8B-aligned (b64-safe)
#define DTHR 8.0f

__device__ __forceinline__ bf16x8 cvt8(f32x4 a, f32x4 b) {
    bf16x8 r;
#pragma unroll
    for (int j = 0; j < 4; ++j) { r[j] = (__bf16)a[j]; r[4 + j] = (__bf16)b[j]; }
    return r;
}

__global__ __launch_bounds__(256)
void sparse_attn_v14(const float* __restrict__ Q,
                     const float* __restrict__ K,
                     const float* __restrict__ V,
                     float* __restrict__ O)
{
    // XCD-chunked bijective swizzle (512 WGs % 8 == 0)
    const int b  = (int)blockIdx.x;
    const int lg = (b & 7) * 64 + (b >> 3);
    const int bh = lg >> 5;              // 0..15
    const int n0 = (lg & 31) * QG;       // group's first q-block

    const int t    = (int)threadIdx.x;
    const int wave = t >> 6;             // 0..3, owns q-block n0+wave
    const int lane = t & 63;
    const int l15  = lane & 15;
    const int l4   = lane >> 4;          // 0..3
    const int nq   = n0 + wave;

    // double-buffered staged tiles (bf16): K rows x d, V^T d x keys
    __shared__ u16 Kt[2][32][KSTR];      // 9.2 KB
    __shared__ u16 Vt[2][64][VSTR];      // 10.2 KB

    const size_t base = (size_t)bh * SEQ * DIM;
    const float SC = 0.125f * 1.44269504088896340736f;  // d^-0.5 * log2(e)

    // ---- staging coords ----
    const int skrow = t >> 3;            // K: row 0..31
    const int skc   = (t & 7) * 8;       // K: d-chunk start
    const int svkey = (t & 15) * 2;      // V: key pair
    const int svdg  = t >> 4;            // V: d-group 0..15 (4 d's each)

    // ---- Q fragments, pre-scaled (verified v11) ----
    bf16x8 qf[2][2];
#pragma unroll
    for (int rt = 0; rt < 2; ++rt) {
        const float* qp = Q + base + (size_t)(nq * 32 + rt * 16 + l15) * DIM + l4 * 8;
        f32x4 a0 = *(const f32x4*)qp        * SC;
        f32x4 b0 = *(const f32x4*)(qp + 4)  * SC;
        f32x4 a1 = *(const f32x4*)(qp + 32) * SC;
        f32x4 b1 = *(const f32x4*)(qp + 36) * SC;
        qf[rt][0] = cvt8(a0, b0);
        qf[rt][1] = cvt8(a1, b1);
    }

    f32x4 acc[2][4] = {};    // [rt][dt]: O[q=l15][d=dt*16+l4*4+r]
    float m[2]  = {-1e30f, -1e30f};
    float lp[2] = {0.f, 0.f};

    const int kb0 = (n0 >= WIN - 1) ? n0 - (WIN - 1) : 0;
    const int kb1 = n0 + QG - 1;

    // ---- prologue: load + stage first block into buf 0 ----
    f32x4 kra, krb, vra, vrb;
    {
        const float* kp = K + base + (size_t)(kb0 * 32 + skrow) * DIM + skc;
        kra = *(const f32x4*)kp;  krb = *(const f32x4*)(kp + 4);
        const float* vp = V + base + (size_t)(kb0 * 32 + svkey) * DIM + svdg * 4;
        vra = *(const f32x4*)vp;  vrb = *(const f32x4*)(vp + DIM);
    }
    {
        *(bf16x8*)&Kt[0][skrow][skc] = cvt8(kra, krb);
#pragma unroll
        for (int j = 0; j < 4; ++j) {
            u32 w = (u32)__builtin_bit_cast(u16, (__bf16)vra[j])
                  | ((u32)__builtin_bit_cast(u16, (__bf16)vrb[j]) << 16);
            *(u32*)&Vt[0][svdg * 4 + j][svkey] = w;
        }
    }
    __syncthreads();

    int cur = 0;
    for (int kb = kb0; kb <= kb1; ++kb) {
        const bool haveNext = (kb < kb1);

        // ---- issue next block's global loads EARLY (hidden under compute) ----
        if (haveNext) {
            const float* kp = K + base + (size_t)((kb + 1) * 32 + skrow) * DIM + skc;
            kra = *(const f32x4*)kp;  krb = *(const f32x4*)(kp + 4);
            const float* vp = V + base + (size_t)((kb + 1) * 32 + svkey) * DIM + svdg * 4;
            vra = *(const f32x4*)vp;  vrb = *(const f32x4*)(vp + DIM);
        }

        const bool part = (kb <= nq) && (kb >= nq - (WIN - 1));
        if (part) {
            // ---- fragments from LDS (layouts match v11-verified global frags) ----
            bf16x8 kf[2][2];
#pragma unroll
            for (int kh = 0; kh < 2; ++kh)
#pragma unroll
                for (int c = 0; c < 2; ++c)
                    kf[kh][c] = *(const bf16x8*)&Kt[cur][kh * 16 + l15][c * 32 + l4 * 8];

            bf16x8 vf[4];
#pragma unroll
            for (int dt = 0; dt < 4; ++dt) {
                bf16x4 lo = *(const bf16x4*)&Vt[cur][dt * 16 + l15][l4 * 4];
                bf16x4 hi = *(const bf16x4*)&Vt[cur][dt * 16 + l15][16 + l4 * 4];
#pragma unroll
                for (int j = 0; j < 4; ++j) { vf[dt][j] = lo[j]; vf[dt][4 + j] = hi[j]; }
            }

            // ---- swapped QK^T (verified): lane = (q=l15, key-group=l4) ----
            f32x4 s[2][2];
#pragma unroll
            for (int rt = 0; rt < 2; ++rt)
#pragma unroll
                for (int kh = 0; kh < 2; ++kh) {
                    f32x4 a = {};
                    a = __builtin_amdgcn_mfma_f32_16x16x32_bf16(kf[kh][0], qf[rt][0], a, 0, 0, 0);
                    a = __builtin_amdgcn_mfma_f32_16x16x32_bf16(kf[kh][1], qf[rt][1], a, 0, 0, 0);
                    s[rt][kh] = a;
                }

            // ---- causal mask (diagonal block only) ----
            if (kb == nq) {
#pragma unroll
                for (int rt = 0; rt < 2; ++rt)
#pragma unroll
                    for (int kh = 0; kh < 2; ++kh)
#pragma unroll
                        for (int r = 0; r < 4; ++r)
                            if (kh * 16 + l4 * 4 + r > rt * 16 + l15)
                                s[rt][kh][r] = -1e30f;
            }

            // ---- defer-max (verified) ----
            bool ok = true;
#pragma unroll
            for (int rt = 0; rt < 2; ++rt)
#pragma unroll
                for (int kh = 0; kh < 2; ++kh)
#pragma unroll
                    for (int r = 0; r < 4; ++r)
                        ok &= (s[rt][kh][r] <= m[rt] + DTHR);

            if (!__all(ok)) {
#pragma unroll
                for (int rt = 0; rt < 2; ++rt) {
                    float t0 = -1e30f;
#pragma unroll
                    for (int kh = 0; kh < 2; ++kh)
#pragma unroll
                        for (int r = 0; r < 4; ++r) t0 = fmaxf(t0, s[rt][kh][r]);
                    t0 = fmaxf(t0, __shfl_xor(t0, 16));
                    t0 = fmaxf(t0, __shfl_xor(t0, 32));
                    const float mn = fmaxf(m[rt], t0);
                    const float al = exp2f(m[rt] - mn);
                    m[rt] = mn;
                    lp[rt] *= al;
#pragma unroll
                    for (int dt = 0; dt < 4; ++dt)
#pragma unroll
                        for (int r = 0; r < 4; ++r) acc[rt][dt][r] *= al;
                }
            }

            // ---- exp2 + pack P (verified) ----
            bf16x8 pbf[2];
#pragma unroll
            for (int rt = 0; rt < 2; ++rt) {
                float psum = 0.f;
#pragma unroll
                for (int j = 0; j < 8; ++j) {
                    const float p = exp2f(s[rt][j >> 2][j & 3] - m[rt]);
                    psum += p;
                    pbf[rt][j] = (__bf16)p;
                }
                lp[rt] += psum;
            }

            // ---- PV (verified): mfma(A=V_perm, B=P_regs) ----
#pragma unroll
            for (int rt = 0; rt < 2; ++rt)
#pragma unroll
                for (int dt = 0; dt < 4; ++dt)
                    acc[rt][dt] = __builtin_amdgcn_mfma_f32_16x16x32_bf16(
                        vf[dt], pbf[rt], acc[rt][dt], 0, 0, 0);
        }

        // ---- write-late: stage kb+1 into the OTHER buffer ----
        // Hazard: buf[cur^1] was last read in iter kb-1's compute; the barrier
        // at the end of iter kb-1 ordered those reads before these writes.
        if (haveNext) {
            *(bf16x8*)&Kt[cur ^ 1][skrow][skc] = cvt8(kra, krb);
#pragma unroll
            for (int j = 0; j < 4; ++j) {
                u32 w = (u32)__builtin_bit_cast(u16, (__bf16)vra[j])
                      | ((u32)__builtin_bit_cast(u16, (__bf16)vrb[j]) << 16);
                *(u32*)&Vt[cur ^ 1][svdg * 4 + j][svkey] = w;
            }
        }

        __syncthreads();   // writes visible; single barrier per iteration
        cur ^= 1;
    }

    // ---- epilogue: reduce l (2 shuffles), normalize, store (verified v11) ----
#pragma unroll
    for (int rt = 0; rt < 2; ++rt) {
        float ps = lp[rt];
        ps += __shfl_xor(ps, 16);
        ps += __shfl_xor(ps, 32);
        const float inv = 1.0f / ps;
        float* op = O + base + (size_t)(nq * 32 + rt * 16 + l15) * DIM + l4 * 4;
#pragma unroll
        for (int dt = 0; dt < 4; ++dt) {
            f32x4 v;
#pragma unroll
            for (int r = 0; r < 4; ++r) v[r] = acc[rt][dt][r] * inv;
            *(f32x4*)(op + dt * 16) = v;
        }
    }
}

extern "C" void kernel_launch(void* const* d_in, const int* in_sizes, int n_in,
                              void* d_out, int out_size, void* d_ws, size_t ws_size,
                              hipStream_t stream)
{
    const float* Q = (const float*)d_in[0];
    const float* K = (const float*)d_in[1];
    const float* V = (const float*)d_in[2];
    float*       O = (float*)d_out;

    const int nwg = 2 * NH * GROUPS;   // 512 WGs x 256 thr
    hipLaunchKernelGGL(sparse_attn_v14, dim3(nwg), dim3(256), 0, stream,
                       Q, K, V, O);
}